// Round 1
// baseline (1627.668 us; speedup 1.0000x reference)
//
#include <hip/hip_runtime.h>
#include <math.h>

#define NN 1048576
#define EE 4194304
#define TPB 256
#define NBLK 2048
#define NBUCK 256
#define BNODES 4096          // nodes per bucket (NN / NBUCK)
#define CAP 20480            // bucket edge capacity (mean 16384, sigma~128)
constexpr float BN_EPS = 1e-5f;

typedef _Float16 half8  __attribute__((ext_vector_type(8)));
typedef _Float16 half4  __attribute__((ext_vector_type(4)));

// ---- workspace layout (bytes), total 80 MB ----
// h rows are SPLIT: main = 8 halves (16B, dwordx4), tail = 4 halves (8B, dwordx2)
// -> 24B/row gathered instead of 32B padded; per-XCD replicated fetch drops 32->24MB.
#define OFF_SSRC    0u                        // NBUCK*CAP ints = 20 MB
#define OFF_ROWPTR  20971520u                 // N ints = 4 MB
#define OFF_ROWEND  25165824u                 // N ints = 4 MB
#define OFF_CURSOR  29360128u                 // NBUCK ints
#define OFF_STATS   (29360128u + 4096u)       // 10*SS floats
#define OFF_HMA     33554432u                 // N*8 halves = 16 MB (main A)
#define OFF_HTA     50331648u                 // N*4 halves =  8 MB (tail A)
#define OFF_HMB     58720256u                 // N*8 halves = 16 MB (main B)
#define OFF_HTB     75497472u                 // N*4 halves =  8 MB (tail B)
#define OFF_EBUF    33554432u                 // NBUCK*CAP int2 = 40 MB (aliases hA/hB; dead before conv1)
#define SS 384                                // stats slot stride (floats): 24 counters * 16

// ================= init: bucket cursors + stats zero =================
__global__ void k_init(int* __restrict__ cursor, float* __restrict__ stats){
  int t = threadIdx.x;
  cursor[t] = t * CAP;
  for(int i = t; i < 10*SS; i += 256) stats[i] = 0.0f;
}

// ============ pass B: bin edges into 256 buckets by dst>>12 ============
__global__ void k_bucket(const int* __restrict__ src, const int* __restrict__ dst,
                         int* __restrict__ cursor, int2* __restrict__ ebuf){
  __shared__ int hist[NBUCK];
  __shared__ int base[NBUCK];
  int t = threadIdx.x;
  hist[t] = 0;
  __syncthreads();
  int eb = blockIdx.x * 4096;
  int s[16], d[16], r[16];
#pragma unroll
  for(int k=0; k<16; k++){
    int e = eb + k*256 + t;
    s[k] = src[e];
    d[k] = dst[e];
    r[k] = atomicAdd(&hist[d[k] >> 12], 1);
  }
  __syncthreads();
  base[t] = atomicAdd(&cursor[t], hist[t]);
  __syncthreads();
#pragma unroll
  for(int k=0; k<16; k++){
    int b = d[k] >> 12;
    int pos = base[b] + r[k];
    if(pos < (b+1)*CAP)                 // capacity guard (never triggers for this data)
      ebuf[pos] = make_int2(s[k], d[k]);
  }
}

// ===== pass C: per-bucket counting sort -> rowptr/rowend/ssrc =====
__global__ void k_csr(const int2* __restrict__ ebuf, const int* __restrict__ cursor,
                      int* __restrict__ ssrc, int* __restrict__ rowptr,
                      int* __restrict__ rowend){
  __shared__ int hist[BNODES];
  __shared__ int part[256];
  int b = blockIdx.x, t = threadIdx.x;
  int cnt = cursor[b] - b*CAP;
  if(cnt > CAP) cnt = CAP;
  int ebase = b*CAP;
  for(int i=t; i<BNODES; i+=256) hist[i] = 0;
  __syncthreads();
  for(int i=t; i<cnt; i+=256){
    int2 e = ebuf[ebase + i];
    atomicAdd(&hist[e.y & (BNODES-1)], 1);
  }
  __syncthreads();
  int loc[16]; int sum = 0;
#pragma unroll
  for(int j=0; j<16; j++){ loc[j] = hist[t*16 + j]; sum += loc[j]; }
  part[t] = sum;
  __syncthreads();
#pragma unroll
  for(int off=1; off<256; off<<=1){
    int v = (t >= off) ? part[t-off] : 0;
    __syncthreads();
    part[t] += v;
    __syncthreads();
  }
  int run = part[t] - sum;   // exclusive prefix for this thread's 16 nodes
#pragma unroll
  for(int j=0; j<16; j++){
    int n = b*BNODES + t*16 + j;
    rowptr[n] = ebase + run;
    rowend[n] = ebase + run + loc[j];
    hist[t*16 + j] = run;
    run += loc[j];
  }
  __syncthreads();
  for(int i=t; i<cnt; i+=256){
    int2 e = ebuf[ebase + i];
    int pos = atomicAdd(&hist[e.y & (BNODES-1)], 1);
    ssrc[ebase + pos] = e.x;
  }
}

// ================= stats helpers =================
template<int NF>
__device__ __forceinline__ void stats_flush(float* ssum, float* ssq,
                                            float* __restrict__ stats_out){
  __shared__ float sred[2*NF];
#pragma unroll
  for(int f=0; f<NF; f++){
    float a = ssum[f], b = ssq[f];
#pragma unroll
    for(int off=1; off<64; off<<=1){
      a += __shfl_xor(a, off, 64);
      b += __shfl_xor(b, off, 64);
    }
    ssum[f] = a; ssq[f] = b;
  }
  if(threadIdx.x < 2*NF) sred[threadIdx.x] = 0.0f;
  __syncthreads();
  if((threadIdx.x & 63) == 0){
#pragma unroll
    for(int f=0; f<NF; f++){
      atomicAdd(&sred[f],      ssum[f]);
      atomicAdd(&sred[NF + f], ssq[f]);
    }
  }
  __syncthreads();
  if(threadIdx.x < 2*NF)
    atomicAdd(&stats_out[threadIdx.x * 16], sred[threadIdx.x]);  // 64B-spread counters
}

__device__ __forceinline__ void store_row12(_Float16* __restrict__ hm,
                                            _Float16* __restrict__ ht,
                                            int i, const float* ov){
  half8 m; half4 t;
#pragma unroll
  for(int j=0; j<8; j++) m[j] = (_Float16)ov[j];
#pragma unroll
  for(int j=0; j<4; j++) t[j] = (_Float16)ov[8+j];
  *(half8*)(hm + 8*i) = m;
  *(half4*)(ht + 4*i) = t;
}

// ================= conv layer 1: x[N,3] fp32 -> h[N,12] fp16 split =================
__global__ void k_layer1(const float* __restrict__ x,
                         const int* __restrict__ rowptr, const int* __restrict__ rowend,
                         const int* __restrict__ ssrc,
                         const float* __restrict__ Wl1, const float* __restrict__ Wr1,
                         const float* __restrict__ b1,
                         _Float16* __restrict__ hm, _Float16* __restrict__ ht,
                         float* __restrict__ stats_out){
  float ssum[12], ssq[12];
#pragma unroll
  for(int f=0; f<12; f++){ ssum[f]=0.f; ssq[f]=0.f; }
  int stride = gridDim.x*blockDim.x;
  for(int i = blockIdx.x*blockDim.x + threadIdx.x; i < NN; i += stride){
    int st = rowptr[i], en = rowend[i];
    float a0=0.f, a1=0.f, a2=0.f;
    int p = st;
    for(; p+4 <= en; p += 4){
      int s0=ssrc[p], s1=ssrc[p+1], s2=ssrc[p+2], s3=ssrc[p+3];
      float u0=x[3*s0], u1=x[3*s0+1], u2=x[3*s0+2];
      float v0=x[3*s1], v1=x[3*s1+1], v2=x[3*s1+2];
      float w0=x[3*s2], w1=x[3*s2+1], w2=x[3*s2+2];
      float y0=x[3*s3], y1=x[3*s3+1], y2=x[3*s3+2];
      a0 += u0+v0+w0+y0; a1 += u1+v1+w1+y1; a2 += u2+v2+w2+y2;
    }
    for(; p<en; p++){
      int s = ssrc[p];
      a0 += x[3*s]; a1 += x[3*s+1]; a2 += x[3*s+2];
    }
    float inv = (en > st) ? 1.0f/(float)(en-st) : 0.0f;
    a0 *= inv; a1 *= inv; a2 *= inv;
    float x0 = x[3*i], x1 = x[3*i+1], x2 = x[3*i+2];
    float ov[12];
#pragma unroll
    for(int f=0; f<12; f++){
      float o = b1[f]
              + Wl1[3*f]*a0 + Wl1[3*f+1]*a1 + Wl1[3*f+2]*a2
              + Wr1[3*f]*x0 + Wr1[3*f+1]*x1 + Wr1[3*f+2]*x2;
      o = fmaxf(o, 0.0f);
      ov[f] = o; ssum[f] += o; ssq[f] += o*o;
    }
    store_row12(hm, ht, i, ov);
  }
  stats_flush<12>(ssum, ssq, stats_out);
}

// ========== conv layers 2..8: BN folded + SAGE, split fp16 [N,12] -> [N,12] ==========
template<bool STATS>
__global__ void k_layerk(const _Float16* __restrict__ hm_in, const _Float16* __restrict__ ht_in,
                         const int* __restrict__ rowptr, const int* __restrict__ rowend,
                         const int* __restrict__ ssrc,
                         const float* __restrict__ Wl, const float* __restrict__ Wr,
                         const float* __restrict__ bias,
                         const float* __restrict__ bng, const float* __restrict__ bnb,
                         const float* __restrict__ stats_in,
                         _Float16* __restrict__ hm_out, _Float16* __restrict__ ht_out,
                         float* __restrict__ stats_out){
  float sc[12], sh[12];
#pragma unroll
  for(int f=0; f<12; f++){
    float m = stats_in[f*16]      * (1.0f/NN);
    float v = stats_in[(12+f)*16] * (1.0f/NN) - m*m;
    float is = rsqrtf(v + BN_EPS);
    sc[f] = bng[f]*is;
    sh[f] = bnb[f] - m*sc[f];
  }
  float ssum[12], ssq[12];
  if(STATS){
#pragma unroll
    for(int f=0; f<12; f++){ ssum[f]=0.f; ssq[f]=0.f; }
  }
  int stride = gridDim.x*blockDim.x;
  for(int i = blockIdx.x*blockDim.x + threadIdx.x; i < NN; i += stride){
    int st = rowptr[i], en = rowend[i];
    float s[12];
#pragma unroll
    for(int k=0; k<12; k++) s[k]=0.f;
    int p = st;
    for(; p+4 <= en; p += 4){
      int s0=ssrc[p], s1=ssrc[p+1], s2=ssrc[p+2], s3=ssrc[p+3];
      half8 a0 = *(const half8*)(hm_in + 8*s0);
      half8 a1 = *(const half8*)(hm_in + 8*s1);
      half8 a2 = *(const half8*)(hm_in + 8*s2);
      half8 a3 = *(const half8*)(hm_in + 8*s3);
      half4 b0 = *(const half4*)(ht_in + 4*s0);
      half4 b1 = *(const half4*)(ht_in + 4*s1);
      half4 b2 = *(const half4*)(ht_in + 4*s2);
      half4 b3 = *(const half4*)(ht_in + 4*s3);
#pragma unroll
      for(int k=0; k<8; k++)
        s[k] += (float)a0[k] + (float)a1[k] + (float)a2[k] + (float)a3[k];
#pragma unroll
      for(int k=0; k<4; k++)
        s[8+k] += (float)b0[k] + (float)b1[k] + (float)b2[k] + (float)b3[k];
    }
    for(; p<en; p++){
      int sid = ssrc[p];
      half8 q0 = *(const half8*)(hm_in + 8*sid);
      half4 q1 = *(const half4*)(ht_in + 4*sid);
#pragma unroll
      for(int k=0; k<8; k++) s[k] += (float)q0[k];
#pragma unroll
      for(int k=0; k<4; k++) s[8+k] += (float)q1[k];
    }
    float inv   = (en > st) ? 1.0f/(float)(en-st) : 0.0f;
    float zmask = (en > st) ? 1.0f : 0.0f;
    half8 r0 = *(const half8*)(hm_in + 8*i);
    half4 r1 = *(const half4*)(ht_in + 4*i);
    float hi[12];
#pragma unroll
    for(int k=0; k<8; k++) hi[k] = (float)r0[k];
#pragma unroll
    for(int k=0; k<4; k++) hi[8+k] = (float)r1[k];
    float aggn[12], hn[12];
#pragma unroll
    for(int k=0; k<12; k++){
      aggn[k] = (s[k]*inv*sc[k] + sh[k]) * zmask;  // mean-of-BN'd == BN-of-mean; deg=0 -> 0
      hn[k]   = hi[k]*sc[k] + sh[k];
    }
    float ov[12];
#pragma unroll
    for(int f=0; f<12; f++){
      float o = bias[f];
#pragma unroll
      for(int k=0; k<12; k++) o += Wl[12*f+k]*aggn[k];
#pragma unroll
      for(int k=0; k<12; k++) o += Wr[12*f+k]*hn[k];
      o = fmaxf(o, 0.0f);
      ov[f] = o;
      if(STATS){ ssum[f] += o; ssq[f] += o*o; }
    }
    store_row12(hm_out, ht_out, i, ov);
  }
  if(STATS) stats_flush<12>(ssum, ssq, stats_out);
}

// ========== head linear on [2N,6] stored as split fp16 [N,12] ==========
// one thread = one split row = two consecutive [2N,6] sub-rows
template<bool FIRST>
__global__ void k_head(const _Float16* __restrict__ zm_in, const _Float16* __restrict__ zt_in,
                       const float* __restrict__ W, const float* __restrict__ bv,
                       const float* __restrict__ g6, const float* __restrict__ b6,
                       const float* __restrict__ stats_in,
                       _Float16* __restrict__ zm_out, _Float16* __restrict__ zt_out,
                       float* __restrict__ stats_out){
  float sc[6], sh[6];
  if(!FIRST){
#pragma unroll
    for(int k=0; k<6; k++){
      float m = stats_in[k*16]     * (1.0f/(2.0f*NN));
      float v = stats_in[(6+k)*16] * (1.0f/(2.0f*NN)) - m*m;
      float is = rsqrtf(v + BN_EPS);
      sc[k] = g6[k]*is;
      sh[k] = b6[k] - m*sc[k];
    }
  }
  float ssum[6], ssq[6];
#pragma unroll
  for(int f=0; f<6; f++){ ssum[f]=0.f; ssq[f]=0.f; }
  int stride = gridDim.x*blockDim.x;
  for(int i = blockIdx.x*blockDim.x + threadIdx.x; i < NN; i += stride){
    half8 a = *(const half8*)(zm_in + 8*i);
    half4 b = *(const half4*)(zt_in + 4*i);
    float t0[6] = {(float)a[0],(float)a[1],(float)a[2],(float)a[3],(float)a[4],(float)a[5]};
    float t1[6] = {(float)a[6],(float)a[7],(float)b[0],(float)b[1],(float)b[2],(float)b[3]};
    if(!FIRST){
#pragma unroll
      for(int k=0; k<6; k++){
        t0[k] = fmaxf(t0[k]*sc[k] + sh[k], 0.0f);
        t1[k] = fmaxf(t1[k]*sc[k] + sh[k], 0.0f);
      }
    }
    float ov[12];
#pragma unroll
    for(int f=0; f<6; f++){
      float o0 = bv[f], o1 = bv[f];
#pragma unroll
      for(int k=0; k<6; k++){ o0 += W[6*f+k]*t0[k]; o1 += W[6*f+k]*t1[k]; }
      ov[f] = o0; ov[6+f] = o1;
      ssum[f] += o0 + o1; ssq[f] += o0*o0 + o1*o1;
    }
    store_row12(zm_out, zt_out, i, ov);
  }
  stats_flush<6>(ssum, ssq, stats_out);
}

// ========== final: BN+ReLU + Linear(6,1) + sigmoid; one thread = 2 outputs ==========
__global__ void k_out(const _Float16* __restrict__ zm_in, const _Float16* __restrict__ zt_in,
                      const float* __restrict__ g6, const float* __restrict__ b6,
                      const float* __restrict__ stats_in,
                      const float* __restrict__ outW, const float* __restrict__ outb,
                      float* __restrict__ out){
  float sc[6], sh[6], w[6];
#pragma unroll
  for(int k=0; k<6; k++){
    float m = stats_in[k*16]     * (1.0f/(2.0f*NN));
    float v = stats_in[(6+k)*16] * (1.0f/(2.0f*NN)) - m*m;
    float is = rsqrtf(v + BN_EPS);
    sc[k] = g6[k]*is;
    sh[k] = b6[k] - m*sc[k];
    w[k] = outW[k];
  }
  float ob = outb[0];
  int stride = gridDim.x*blockDim.x;
  for(int i = blockIdx.x*blockDim.x + threadIdx.x; i < NN; i += stride){
    half8 a = *(const half8*)(zm_in + 8*i);
    half4 b = *(const half4*)(zt_in + 4*i);
    float t0[6] = {(float)a[0],(float)a[1],(float)a[2],(float)a[3],(float)a[4],(float)a[5]};
    float t1[6] = {(float)a[6],(float)a[7],(float)b[0],(float)b[1],(float)b[2],(float)b[3]};
    float o0 = ob, o1 = ob;
#pragma unroll
    for(int k=0; k<6; k++){
      o0 += w[k] * fmaxf(t0[k]*sc[k] + sh[k], 0.0f);
      o1 += w[k] * fmaxf(t1[k]*sc[k] + sh[k], 0.0f);
    }
    float2 r;
    r.x = 1.0f / (1.0f + expf(-o0));
    r.y = 1.0f / (1.0f + expf(-o1));
    ((float2*)out)[i] = r;
  }
}

extern "C" void kernel_launch(void* const* d_in, const int* in_sizes, int n_in,
                              void* d_out, int out_size, void* d_ws, size_t ws_size,
                              hipStream_t stream){
  const float* x    = (const float*)d_in[0];
  const int*   ei   = (const int*)  d_in[1];
  const float* Wl1  = (const float*)d_in[2];
  const float* Wr1  = (const float*)d_in[3];
  const float* b1   = (const float*)d_in[4];
  const float* Wl   = (const float*)d_in[5];
  const float* Wr   = (const float*)d_in[6];
  const float* bb   = (const float*)d_in[7];
  const float* bng  = (const float*)d_in[8];
  const float* bnb  = (const float*)d_in[9];
  const float* linW = (const float*)d_in[10];
  const float* linb = (const float*)d_in[11];
  const float* bn6g = (const float*)d_in[12];
  const float* bn6b = (const float*)d_in[13];
  const float* outW = (const float*)d_in[14];
  const float* outb = (const float*)d_in[15];
  float* out = (float*)d_out;

  char* ws = (char*)d_ws;
  int*      ssrc   = (int*)     (ws + OFF_SSRC);
  int*      rowptr = (int*)     (ws + OFF_ROWPTR);
  int*      rowend = (int*)     (ws + OFF_ROWEND);
  int*      cursor = (int*)     (ws + OFF_CURSOR);
  float*    stats  = (float*)   (ws + OFF_STATS);
  _Float16* hmA    = (_Float16*)(ws + OFF_HMA);
  _Float16* htA    = (_Float16*)(ws + OFF_HTA);
  _Float16* hmB    = (_Float16*)(ws + OFF_HMB);
  _Float16* htB    = (_Float16*)(ws + OFF_HTB);
  int2*     ebuf   = (int2*)    (ws + OFF_EBUF);   // aliases hA/hB; dead after k_csr

  const int* srcp = ei;
  const int* dstp = ei + EE;

  k_init  <<<1,    256, 0, stream>>>(cursor, stats);
  k_bucket<<<1024, 256, 0, stream>>>(srcp, dstp, cursor, ebuf);
  k_csr   <<<NBUCK,256, 0, stream>>>(ebuf, cursor, ssrc, rowptr, rowend);

  // conv1 (stats -> slot 0)
  k_layer1<<<NBLK, TPB, 0, stream>>>(x, rowptr, rowend, ssrc, Wl1, Wr1, b1,
                                     hmA, htA, stats);

  // conv2..conv8
  _Float16* him = hmA; _Float16* hit = htA;
  _Float16* hom = hmB; _Float16* hot = htB;
  for(int l=0; l<7; l++){
    const float* st_in = stats + l*SS;
    float* st_out      = stats + (l+1)*SS;
    if(l < 6)
      k_layerk<true><<<NBLK, TPB, 0, stream>>>(him, hit, rowptr, rowend, ssrc,
        Wl + 144*l, Wr + 144*l, bb + 12*l, bng + 12*l, bnb + 12*l, st_in,
        hom, hot, st_out);
    else
      k_layerk<false><<<NBLK, TPB, 0, stream>>>(him, hit, rowptr, rowend, ssrc,
        Wl + 144*l, Wr + 144*l, bb + 12*l, bng + 12*l, bnb + 12*l, st_in,
        hom, hot, st_out);
    _Float16* t;
    t = him; him = hom; hom = t;
    t = hit; hit = hot; hot = t;
  }
  // him/hit = conv8 output; head views each row as two [2N,6] sub-rows

  // head: z1 (stats slot 7)
  k_head<true> <<<NBLK, TPB, 0, stream>>>(him, hit, linW, linb, bn6g, bn6b,
                                          stats + 7*SS, hom, hot, stats + 7*SS);
  { _Float16* t; t = him; him = hom; hom = t; t = hit; hit = hot; hot = t; }
  // z2 (slot 8)
  k_head<false><<<NBLK, TPB, 0, stream>>>(him, hit, linW, linb, bn6g, bn6b,
                                          stats + 7*SS, hom, hot, stats + 8*SS);
  { _Float16* t; t = him; him = hom; hom = t; t = hit; hit = hot; hot = t; }
  // z3 (slot 9)
  k_head<false><<<NBLK, TPB, 0, stream>>>(him, hit, linW, linb, bn6g, bn6b,
                                          stats + 8*SS, hom, hot, stats + 9*SS);
  { _Float16* t; t = him; him = hom; hom = t; t = hit; hit = hot; hot = t; }
  // final
  k_out<<<NBLK, TPB, 0, stream>>>(him, hit, bn6g, bn6b, stats + 9*SS, outW, outb, out);
}

// Round 2
// 1371.054 us; speedup vs baseline: 1.1872x; 1.1872x over previous
//
#include <hip/hip_runtime.h>
#include <math.h>

#define NN 1048576
#define EE 4194304
#define TPB 256
#define NBLK 2048
#define NBUCK 256
#define BNODES 4096          // nodes per bucket (NN / NBUCK)
#define CAP 20480            // bucket edge capacity (mean 16384, sigma~128)
constexpr float BN_EPS = 1e-5f;

typedef _Float16 half8  __attribute__((ext_vector_type(8)));

// ---- workspace layout (bytes), total 96 MB ----
// h rows are PADDED to 32B (16 halves): ONE 64B-line touch per random gather.
// (Round-1 lesson: random-gather cost = line touches x 64B, not useful bytes.)
#define OFF_SSRC    0u                        // NBUCK*CAP ints = 20 MB
#define OFF_ROWPTR  20971520u                 // N ints = 4 MB
#define OFF_ROWEND  25165824u                 // N ints = 4 MB
#define OFF_CURSOR  29360128u                 // NBUCK ints
#define OFF_STATS   (29360128u + 4096u)       // 10*SS floats
#define OFF_HA      33554432u                 // N*16 halves = 32 MB
#define OFF_HB      67108864u                 // N*16 halves = 32 MB
#define OFF_EBUF    33554432u                 // NBUCK*CAP int2 = 40 MB (aliases hA/hB; dead before conv1)
#define SS 384                                // stats slot stride (floats): 24 counters * 16

// ================= init: bucket cursors + stats zero =================
__global__ void k_init(int* __restrict__ cursor, float* __restrict__ stats){
  int t = threadIdx.x;
  cursor[t] = t * CAP;
  for(int i = t; i < 10*SS; i += 256) stats[i] = 0.0f;
}

// ============ pass B: bin edges into 256 buckets by dst>>12 ============
__global__ void k_bucket(const int* __restrict__ src, const int* __restrict__ dst,
                         int* __restrict__ cursor, int2* __restrict__ ebuf){
  __shared__ int hist[NBUCK];
  __shared__ int base[NBUCK];
  int t = threadIdx.x;
  hist[t] = 0;
  __syncthreads();
  int eb = blockIdx.x * 4096;
  int s[16], d[16], r[16];
#pragma unroll
  for(int k=0; k<16; k++){
    int e = eb + k*256 + t;
    s[k] = src[e];
    d[k] = dst[e];
    r[k] = atomicAdd(&hist[d[k] >> 12], 1);
  }
  __syncthreads();
  base[t] = atomicAdd(&cursor[t], hist[t]);
  __syncthreads();
#pragma unroll
  for(int k=0; k<16; k++){
    int b = d[k] >> 12;
    int pos = base[b] + r[k];
    if(pos < (b+1)*CAP)                 // capacity guard (never triggers for this data)
      ebuf[pos] = make_int2(s[k], d[k]);
  }
}

// ===== pass C: per-bucket counting sort -> rowptr/rowend/ssrc =====
__global__ void k_csr(const int2* __restrict__ ebuf, const int* __restrict__ cursor,
                      int* __restrict__ ssrc, int* __restrict__ rowptr,
                      int* __restrict__ rowend){
  __shared__ int hist[BNODES];
  __shared__ int part[256];
  int b = blockIdx.x, t = threadIdx.x;
  int cnt = cursor[b] - b*CAP;
  if(cnt > CAP) cnt = CAP;
  int ebase = b*CAP;
  for(int i=t; i<BNODES; i+=256) hist[i] = 0;
  __syncthreads();
  for(int i=t; i<cnt; i+=256){
    int2 e = ebuf[ebase + i];
    atomicAdd(&hist[e.y & (BNODES-1)], 1);
  }
  __syncthreads();
  int loc[16]; int sum = 0;
#pragma unroll
  for(int j=0; j<16; j++){ loc[j] = hist[t*16 + j]; sum += loc[j]; }
  part[t] = sum;
  __syncthreads();
#pragma unroll
  for(int off=1; off<256; off<<=1){
    int v = (t >= off) ? part[t-off] : 0;
    __syncthreads();
    part[t] += v;
    __syncthreads();
  }
  int run = part[t] - sum;   // exclusive prefix for this thread's 16 nodes
#pragma unroll
  for(int j=0; j<16; j++){
    int n = b*BNODES + t*16 + j;
    rowptr[n] = ebase + run;
    rowend[n] = ebase + run + loc[j];
    hist[t*16 + j] = run;
    run += loc[j];
  }
  __syncthreads();
  for(int i=t; i<cnt; i+=256){
    int2 e = ebuf[ebase + i];
    int pos = atomicAdd(&hist[e.y & (BNODES-1)], 1);
    ssrc[ebase + pos] = e.x;
  }
}

// ================= stats helpers =================
template<int NF>
__device__ __forceinline__ void stats_flush(float* ssum, float* ssq,
                                            float* __restrict__ stats_out){
  __shared__ float sred[2*NF];
#pragma unroll
  for(int f=0; f<NF; f++){
    float a = ssum[f], b = ssq[f];
#pragma unroll
    for(int off=1; off<64; off<<=1){
      a += __shfl_xor(a, off, 64);
      b += __shfl_xor(b, off, 64);
    }
    ssum[f] = a; ssq[f] = b;
  }
  if(threadIdx.x < 2*NF) sred[threadIdx.x] = 0.0f;
  __syncthreads();
  if((threadIdx.x & 63) == 0){
#pragma unroll
    for(int f=0; f<NF; f++){
      atomicAdd(&sred[f],      ssum[f]);
      atomicAdd(&sred[NF + f], ssq[f]);
    }
  }
  __syncthreads();
  if(threadIdx.x < 2*NF)
    atomicAdd(&stats_out[threadIdx.x * 16], sred[threadIdx.x]);  // 64B-spread counters
}

__device__ __forceinline__ void store_row16(_Float16* __restrict__ hout, int i,
                                            const float* ov){
  half8 o0, o1;
#pragma unroll
  for(int j=0; j<8; j++) o0[j] = (_Float16)ov[j];
#pragma unroll
  for(int j=0; j<4; j++) o1[j] = (_Float16)ov[8+j];
  o1[4]=(_Float16)0.f; o1[5]=(_Float16)0.f; o1[6]=(_Float16)0.f; o1[7]=(_Float16)0.f;
  half8* op = (half8*)(hout + 16*i);
  op[0] = o0; op[1] = o1;
}

// ================= conv layer 1: x[N,3] fp32 -> h[N,16] fp16 =================
__global__ void k_layer1(const float* __restrict__ x,
                         const int* __restrict__ rowptr, const int* __restrict__ rowend,
                         const int* __restrict__ ssrc,
                         const float* __restrict__ Wl1, const float* __restrict__ Wr1,
                         const float* __restrict__ b1,
                         _Float16* __restrict__ hout, float* __restrict__ stats_out){
  float ssum[12], ssq[12];
#pragma unroll
  for(int f=0; f<12; f++){ ssum[f]=0.f; ssq[f]=0.f; }
  int stride = gridDim.x*blockDim.x;
  for(int i = blockIdx.x*blockDim.x + threadIdx.x; i < NN; i += stride){
    int st = rowptr[i], en = rowend[i];
    float a0=0.f, a1=0.f, a2=0.f;
    int p = st;
    for(; p+4 <= en; p += 4){
      int s0=ssrc[p], s1=ssrc[p+1], s2=ssrc[p+2], s3=ssrc[p+3];
      float u0=x[3*s0], u1=x[3*s0+1], u2=x[3*s0+2];
      float v0=x[3*s1], v1=x[3*s1+1], v2=x[3*s1+2];
      float w0=x[3*s2], w1=x[3*s2+1], w2=x[3*s2+2];
      float y0=x[3*s3], y1=x[3*s3+1], y2=x[3*s3+2];
      a0 += u0+v0+w0+y0; a1 += u1+v1+w1+y1; a2 += u2+v2+w2+y2;
    }
    for(; p<en; p++){
      int s = ssrc[p];
      a0 += x[3*s]; a1 += x[3*s+1]; a2 += x[3*s+2];
    }
    float inv = (en > st) ? 1.0f/(float)(en-st) : 0.0f;
    a0 *= inv; a1 *= inv; a2 *= inv;
    float x0 = x[3*i], x1 = x[3*i+1], x2 = x[3*i+2];
    float ov[12];
#pragma unroll
    for(int f=0; f<12; f++){
      float o = b1[f]
              + Wl1[3*f]*a0 + Wl1[3*f+1]*a1 + Wl1[3*f+2]*a2
              + Wr1[3*f]*x0 + Wr1[3*f+1]*x1 + Wr1[3*f+2]*x2;
      o = fmaxf(o, 0.0f);
      ov[f] = o; ssum[f] += o; ssq[f] += o*o;
    }
    store_row16(hout, i, ov);
  }
  stats_flush<12>(ssum, ssq, stats_out);
}

// ========== conv layers 2..8: BN folded + SAGE, fp16 [N,16] -> fp16 [N,16] ==========
// One thread = TWO consecutive nodes. All 16 gather loads + 2 root loads for the
// pair are issued before any accumulation (2x per-thread MLP vs 1-node version).
// Uniform 4-edge chunks via clamped indices: gather min(p+j,en-1), then subtract
// the over-counted last row max(p+4-en,0) times (exact in fp32; deg=0 cancels to 0).
template<bool STATS>
__global__ void __launch_bounds__(256, 3)
k_layerk(const _Float16* __restrict__ hin,
         const int* __restrict__ rowptr, const int* __restrict__ rowend,
         const int* __restrict__ ssrc,
         const float* __restrict__ Wl, const float* __restrict__ Wr,
         const float* __restrict__ bias,
         const float* __restrict__ bng, const float* __restrict__ bnb,
         const float* __restrict__ stats_in,
         _Float16* __restrict__ hout, float* __restrict__ stats_out){
  float sc[12], sh[12];
#pragma unroll
  for(int f=0; f<12; f++){
    float m = stats_in[f*16]      * (1.0f/NN);
    float v = stats_in[(12+f)*16] * (1.0f/NN) - m*m;
    float is = rsqrtf(v + BN_EPS);
    sc[f] = bng[f]*is;
    sh[f] = bnb[f] - m*sc[f];
  }
  float ssum[12], ssq[12];
  if(STATS){
#pragma unroll
    for(int f=0; f<12; f++){ ssum[f]=0.f; ssq[f]=0.f; }
  }
  int stride = gridDim.x*blockDim.x;
  for(int ii = blockIdx.x*blockDim.x + threadIdx.x; ii < NN/2; ii += stride){
    int i0 = 2*ii, i1 = i0 + 1;
    int2 rp = *(const int2*)(rowptr + i0);   // i0 even -> 8B aligned
    int2 re = *(const int2*)(rowend + i0);
    int stA = rp.x, enA = re.x, stB = rp.y, enB = re.y;

    // --- first-chunk ssrc indices (clamped); deg=0 self-gathers (cancels) ---
    int a0,a1,a2,a3, b0,b1,b2,b3;
    if(stA < enA){
      int m = enA - 1;
      a0 = ssrc[stA];
      a1 = ssrc[min(stA+1, m)];
      a2 = ssrc[min(stA+2, m)];
      a3 = ssrc[min(stA+3, m)];
    } else { a0=a1=a2=a3=i0; }
    if(stB < enB){
      int m = enB - 1;
      b0 = ssrc[stB];
      b1 = ssrc[min(stB+1, m)];
      b2 = ssrc[min(stB+2, m)];
      b3 = ssrc[min(stB+3, m)];
    } else { b0=b1=b2=b3=i1; }

    // --- issue all 16 gather loads + 4 root loads back-to-back ---
    const half8* pA0 = (const half8*)(hin + 16*a0);
    const half8* pA1 = (const half8*)(hin + 16*a1);
    const half8* pA2 = (const half8*)(hin + 16*a2);
    const half8* pA3 = (const half8*)(hin + 16*a3);
    const half8* pB0 = (const half8*)(hin + 16*b0);
    const half8* pB1 = (const half8*)(hin + 16*b1);
    const half8* pB2 = (const half8*)(hin + 16*b2);
    const half8* pB3 = (const half8*)(hin + 16*b3);
    const half8* pR0 = (const half8*)(hin + 16*i0);
    const half8* pR1 = (const half8*)(hin + 16*i1);
    half8 rA0=pA0[0], rA0h=pA0[1];
    half8 rA1=pA1[0], rA1h=pA1[1];
    half8 rA2=pA2[0], rA2h=pA2[1];
    half8 rA3=pA3[0], rA3h=pA3[1];
    half8 rB0=pB0[0], rB0h=pB0[1];
    half8 rB1=pB1[0], rB1h=pB1[1];
    half8 rB2=pB2[0], rB2h=pB2[1];
    half8 rB3=pB3[0], rB3h=pB3[1];
    half8 rR0=pR0[0], rR0h=pR0[1];
    half8 rR1=pR1[0], rR1h=pR1[1];

    // --- accumulate pair chunk (over-count corrected) ---
    float sA[12], sB[12];
    float subA = (float)max(stA + 4 - enA, 0);
    float subB = (float)max(stB + 4 - enB, 0);
#pragma unroll
    for(int k=0; k<8; k++){
      float l3 = (float)rA3[k];
      sA[k] = ((float)rA0[k] + (float)rA1[k]) + ((float)rA2[k] + l3) - subA*l3;
    }
#pragma unroll
    for(int k=0; k<4; k++){
      float l3 = (float)rA3h[k];
      sA[8+k] = ((float)rA0h[k] + (float)rA1h[k]) + ((float)rA2h[k] + l3) - subA*l3;
    }
#pragma unroll
    for(int k=0; k<8; k++){
      float l3 = (float)rB3[k];
      sB[k] = ((float)rB0[k] + (float)rB1[k]) + ((float)rB2[k] + l3) - subB*l3;
    }
#pragma unroll
    for(int k=0; k<4; k++){
      float l3 = (float)rB3h[k];
      sB[8+k] = ((float)rB0h[k] + (float)rB1h[k]) + ((float)rB2h[k] + l3) - subB*l3;
    }

    // --- tails (deg > 4), uniform clamped chunks ---
    for(int p = stA + 4; p < enA; p += 4){
      int m = enA - 1;
      int s0 = ssrc[p];
      int s1 = ssrc[min(p+1, m)];
      int s2 = ssrc[min(p+2, m)];
      int s3 = ssrc[min(p+3, m)];
      const half8* h0 = (const half8*)(hin + 16*s0);
      const half8* h1 = (const half8*)(hin + 16*s1);
      const half8* h2 = (const half8*)(hin + 16*s2);
      const half8* h3 = (const half8*)(hin + 16*s3);
      half8 q0=h0[0], q0h=h0[1];
      half8 q1=h1[0], q1h=h1[1];
      half8 q2=h2[0], q2h=h2[1];
      half8 q3=h3[0], q3h=h3[1];
      float sub = (float)max(p + 4 - enA, 0);
#pragma unroll
      for(int k=0; k<8; k++){
        float l3 = (float)q3[k];
        sA[k] += ((float)q0[k] + (float)q1[k]) + ((float)q2[k] + l3) - sub*l3;
      }
#pragma unroll
      for(int k=0; k<4; k++){
        float l3 = (float)q3h[k];
        sA[8+k] += ((float)q0h[k] + (float)q1h[k]) + ((float)q2h[k] + l3) - sub*l3;
      }
    }
    for(int p = stB + 4; p < enB; p += 4){
      int m = enB - 1;
      int s0 = ssrc[p];
      int s1 = ssrc[min(p+1, m)];
      int s2 = ssrc[min(p+2, m)];
      int s3 = ssrc[min(p+3, m)];
      const half8* h0 = (const half8*)(hin + 16*s0);
      const half8* h1 = (const half8*)(hin + 16*s1);
      const half8* h2 = (const half8*)(hin + 16*s2);
      const half8* h3 = (const half8*)(hin + 16*s3);
      half8 q0=h0[0], q0h=h0[1];
      half8 q1=h1[0], q1h=h1[1];
      half8 q2=h2[0], q2h=h2[1];
      half8 q3=h3[0], q3h=h3[1];
      float sub = (float)max(p + 4 - enB, 0);
#pragma unroll
      for(int k=0; k<8; k++){
        float l3 = (float)q3[k];
        sB[k] += ((float)q0[k] + (float)q1[k]) + ((float)q2[k] + l3) - sub*l3;
      }
#pragma unroll
      for(int k=0; k<4; k++){
        float l3 = (float)q3h[k];
        sB[8+k] += ((float)q0h[k] + (float)q1h[k]) + ((float)q2h[k] + l3) - sub*l3;
      }
    }

    // --- BN-fold + MLP + ReLU + store, node A then node B ---
    {
      int d = enA - stA;
      float inv   = (d > 0) ? 1.0f/(float)d : 0.0f;
      float zmask = (d > 0) ? 1.0f : 0.0f;
      float hi[12];
#pragma unroll
      for(int k=0; k<8; k++) hi[k] = (float)rR0[k];
#pragma unroll
      for(int k=0; k<4; k++) hi[8+k] = (float)rR0h[k];
      float aggn[12], hn[12];
#pragma unroll
      for(int k=0; k<12; k++){
        aggn[k] = (sA[k]*inv*sc[k] + sh[k]) * zmask;
        hn[k]   = hi[k]*sc[k] + sh[k];
      }
      float ov[12];
#pragma unroll
      for(int f=0; f<12; f++){
        float o = bias[f];
#pragma unroll
        for(int k=0; k<12; k++) o += Wl[12*f+k]*aggn[k];
#pragma unroll
        for(int k=0; k<12; k++) o += Wr[12*f+k]*hn[k];
        o = fmaxf(o, 0.0f);
        ov[f] = o;
        if(STATS){ ssum[f] += o; ssq[f] += o*o; }
      }
      store_row16(hout, i0, ov);
    }
    {
      int d = enB - stB;
      float inv   = (d > 0) ? 1.0f/(float)d : 0.0f;
      float zmask = (d > 0) ? 1.0f : 0.0f;
      float hi[12];
#pragma unroll
      for(int k=0; k<8; k++) hi[k] = (float)rR1[k];
#pragma unroll
      for(int k=0; k<4; k++) hi[8+k] = (float)rR1h[k];
      float aggn[12], hn[12];
#pragma unroll
      for(int k=0; k<12; k++){
        aggn[k] = (sB[k]*inv*sc[k] + sh[k]) * zmask;
        hn[k]   = hi[k]*sc[k] + sh[k];
      }
      float ov[12];
#pragma unroll
      for(int f=0; f<12; f++){
        float o = bias[f];
#pragma unroll
        for(int k=0; k<12; k++) o += Wl[12*f+k]*aggn[k];
#pragma unroll
        for(int k=0; k<12; k++) o += Wr[12*f+k]*hn[k];
        o = fmaxf(o, 0.0f);
        ov[f] = o;
        if(STATS){ ssum[f] += o; ssq[f] += o*o; }
      }
      store_row16(hout, i1, ov);
    }
  }
  if(STATS) stats_flush<12>(ssum, ssq, stats_out);
}

// ========== head linear on [2N,6] stored as padded fp16 [N,16] ==========
// one thread = one padded row = two consecutive [2N,6] sub-rows
template<bool FIRST>
__global__ void k_head(const _Float16* __restrict__ zin,
                       const float* __restrict__ W, const float* __restrict__ bv,
                       const float* __restrict__ g6, const float* __restrict__ b6,
                       const float* __restrict__ stats_in,
                       _Float16* __restrict__ zout, float* __restrict__ stats_out){
  float sc[6], sh[6];
  if(!FIRST){
#pragma unroll
    for(int k=0; k<6; k++){
      float m = stats_in[k*16]     * (1.0f/(2.0f*NN));
      float v = stats_in[(6+k)*16] * (1.0f/(2.0f*NN)) - m*m;
      float is = rsqrtf(v + BN_EPS);
      sc[k] = g6[k]*is;
      sh[k] = b6[k] - m*sc[k];
    }
  }
  float ssum[6], ssq[6];
#pragma unroll
  for(int f=0; f<6; f++){ ssum[f]=0.f; ssq[f]=0.f; }
  int stride = gridDim.x*blockDim.x;
  for(int i = blockIdx.x*blockDim.x + threadIdx.x; i < NN; i += stride){
    const half8* zp = (const half8*)(zin + 16*i);
    half8 a = zp[0], b = zp[1];
    float t0[6] = {(float)a[0],(float)a[1],(float)a[2],(float)a[3],(float)a[4],(float)a[5]};
    float t1[6] = {(float)a[6],(float)a[7],(float)b[0],(float)b[1],(float)b[2],(float)b[3]};
    if(!FIRST){
#pragma unroll
      for(int k=0; k<6; k++){
        t0[k] = fmaxf(t0[k]*sc[k] + sh[k], 0.0f);
        t1[k] = fmaxf(t1[k]*sc[k] + sh[k], 0.0f);
      }
    }
    float ov[12];
#pragma unroll
    for(int f=0; f<6; f++){
      float o0 = bv[f], o1 = bv[f];
#pragma unroll
      for(int k=0; k<6; k++){ o0 += W[6*f+k]*t0[k]; o1 += W[6*f+k]*t1[k]; }
      ov[f] = o0; ov[6+f] = o1;
      ssum[f] += o0 + o1; ssq[f] += o0*o0 + o1*o1;
    }
    store_row16(zout, i, ov);
  }
  stats_flush<6>(ssum, ssq, stats_out);
}

// ========== final: BN+ReLU + Linear(6,1) + sigmoid; one thread = 2 outputs ==========
__global__ void k_out(const _Float16* __restrict__ zin,
                      const float* __restrict__ g6, const float* __restrict__ b6,
                      const float* __restrict__ stats_in,
                      const float* __restrict__ outW, const float* __restrict__ outb,
                      float* __restrict__ out){
  float sc[6], sh[6], w[6];
#pragma unroll
  for(int k=0; k<6; k++){
    float m = stats_in[k*16]     * (1.0f/(2.0f*NN));
    float v = stats_in[(6+k)*16] * (1.0f/(2.0f*NN)) - m*m;
    float is = rsqrtf(v + BN_EPS);
    sc[k] = g6[k]*is;
    sh[k] = b6[k] - m*sc[k];
    w[k] = outW[k];
  }
  float ob = outb[0];
  int stride = gridDim.x*blockDim.x;
  for(int i = blockIdx.x*blockDim.x + threadIdx.x; i < NN; i += stride){
    const half8* zp = (const half8*)(zin + 16*i);
    half8 a = zp[0], b = zp[1];
    float t0[6] = {(float)a[0],(float)a[1],(float)a[2],(float)a[3],(float)a[4],(float)a[5]};
    float t1[6] = {(float)a[6],(float)a[7],(float)b[0],(float)b[1],(float)b[2],(float)b[3]};
    float o0 = ob, o1 = ob;
#pragma unroll
    for(int k=0; k<6; k++){
      o0 += w[k] * fmaxf(t0[k]*sc[k] + sh[k], 0.0f);
      o1 += w[k] * fmaxf(t1[k]*sc[k] + sh[k], 0.0f);
    }
    float2 r;
    r.x = 1.0f / (1.0f + expf(-o0));
    r.y = 1.0f / (1.0f + expf(-o1));
    ((float2*)out)[i] = r;
  }
}

extern "C" void kernel_launch(void* const* d_in, const int* in_sizes, int n_in,
                              void* d_out, int out_size, void* d_ws, size_t ws_size,
                              hipStream_t stream){
  const float* x    = (const float*)d_in[0];
  const int*   ei   = (const int*)  d_in[1];
  const float* Wl1  = (const float*)d_in[2];
  const float* Wr1  = (const float*)d_in[3];
  const float* b1   = (const float*)d_in[4];
  const float* Wl   = (const float*)d_in[5];
  const float* Wr   = (const float*)d_in[6];
  const float* bb   = (const float*)d_in[7];
  const float* bng  = (const float*)d_in[8];
  const float* bnb  = (const float*)d_in[9];
  const float* linW = (const float*)d_in[10];
  const float* linb = (const float*)d_in[11];
  const float* bn6g = (const float*)d_in[12];
  const float* bn6b = (const float*)d_in[13];
  const float* outW = (const float*)d_in[14];
  const float* outb = (const float*)d_in[15];
  float* out = (float*)d_out;

  char* ws = (char*)d_ws;
  int*      ssrc   = (int*)     (ws + OFF_SSRC);
  int*      rowptr = (int*)     (ws + OFF_ROWPTR);
  int*      rowend = (int*)     (ws + OFF_ROWEND);
  int*      cursor = (int*)     (ws + OFF_CURSOR);
  float*    stats  = (float*)   (ws + OFF_STATS);
  _Float16* hA     = (_Float16*)(ws + OFF_HA);
  _Float16* hB     = (_Float16*)(ws + OFF_HB);
  int2*     ebuf   = (int2*)    (ws + OFF_EBUF);   // aliases hA/hB; dead after k_csr

  const int* srcp = ei;
  const int* dstp = ei + EE;

  k_init  <<<1,    256, 0, stream>>>(cursor, stats);
  k_bucket<<<1024, 256, 0, stream>>>(srcp, dstp, cursor, ebuf);
  k_csr   <<<NBUCK,256, 0, stream>>>(ebuf, cursor, ssrc, rowptr, rowend);

  // conv1 (stats -> slot 0)
  k_layer1<<<NBLK, TPB, 0, stream>>>(x, rowptr, rowend, ssrc, Wl1, Wr1, b1, hA, stats);

  // conv2..conv8
  _Float16* hi = hA; _Float16* ho = hB;
  for(int l=0; l<7; l++){
    const float* st_in = stats + l*SS;
    float* st_out      = stats + (l+1)*SS;
    if(l < 6)
      k_layerk<true><<<NBLK, TPB, 0, stream>>>(hi, rowptr, rowend, ssrc,
        Wl + 144*l, Wr + 144*l, bb + 12*l, bng + 12*l, bnb + 12*l, st_in, ho, st_out);
    else
      k_layerk<false><<<NBLK, TPB, 0, stream>>>(hi, rowptr, rowend, ssrc,
        Wl + 144*l, Wr + 144*l, bb + 12*l, bng + 12*l, bnb + 12*l, st_in, ho, st_out);
    _Float16* t = hi; hi = ho; ho = t;
  }
  // hi = conv8 output, padded fp16 rows; head views each row as two [2N,6] sub-rows

  // head: z1 (stats slot 7)
  k_head<true> <<<NBLK, TPB, 0, stream>>>(hi, linW, linb, bn6g, bn6b,
                                          stats + 7*SS, ho, stats + 7*SS);
  { _Float16* t = hi; hi = ho; ho = t; }
  // z2 (slot 8)
  k_head<false><<<NBLK, TPB, 0, stream>>>(hi, linW, linb, bn6g, bn6b,
                                          stats + 7*SS, ho, stats + 8*SS);
  { _Float16* t = hi; hi = ho; ho = t; }
  // z3 (slot 9)
  k_head<false><<<NBLK, TPB, 0, stream>>>(hi, linW, linb, bn6g, bn6b,
                                          stats + 8*SS, ho, stats + 9*SS);
  { _Float16* t = hi; hi = ho; ho = t; }
  // final
  k_out<<<NBLK, TPB, 0, stream>>>(hi, bn6g, bn6b, stats + 9*SS, outW, outb, out);
}